// Round 9
// baseline (394.886 us; speedup 1.0000x reference)
//
#include <hip/hip_runtime.h>
#include <hip/hip_bf16.h>
#include <stdint.h>

#define BATCH 8
#define SEQ   4096
#define DM    512
#define HD    120
#define PH    2048   // p-range per attn block
#define NT    32     // tiles per pass (PH/64)

typedef __bf16   v8bf  __attribute__((ext_vector_type(8)));
typedef float    v4f   __attribute__((ext_vector_type(4)));
typedef int      i4    __attribute__((ext_vector_type(4)));
typedef uint32_t u32x2 __attribute__((ext_vector_type(2)));
typedef uint32_t u32x4 __attribute__((ext_vector_type(4)));
typedef float    f32x4 __attribute__((ext_vector_type(4)));

static __device__ __forceinline__ ushort f2bf(float x) {
  uint32_t u = __builtin_bit_cast(uint32_t, x);
  return (ushort)((u + 0x7fffu + ((u >> 16) & 1u)) >> 16);
}

// -------------------------------------------------------------------------
// prep_kernel: 1024 blocks x 256 thr. Even blocks: ctx GEMM -> bf16
// [B*S][128] PRE-SWIZZLED (byte-in-row = slot*16 ^ ((row&7)<<4)). Odd
// blocks: compress 64 mask rows -> bitsT[b][pw 0..127][q 0..4095]
// (transposed via LDS so attn bit-reads are coalesced).
// -------------------------------------------------------------------------
__global__ __launch_bounds__(256) void prep_kernel(
    const float* __restrict__ q, const float* __restrict__ wq,
    const float* __restrict__ bq, const float* __restrict__ wt,
    const int* __restrict__ mask, ushort* __restrict__ ctx,
    uint32_t* __restrict__ bitsT)
{
  __shared__ __align__(16) char smem[33024];
  const int t = threadIdx.x;

  if (blockIdx.x & 1) {
    // ---- mask compression, 64 rows, transposed output ----
    uint32_t (*bw)[129] = (uint32_t(*)[129])smem;  // [64][129]
    const int cb = blockIdx.x >> 1;                // 0..511
    const size_t row0 = (size_t)cb * 64;
    const int b     = (int)(row0 >> 12);
    const int qbase = (int)(row0 & 4095);
    const int rhalf = t >> 7, pw = t & 127;
    for (int s = 0; s < 32; ++s) {
      int row = s * 2 + rhalf;
      const int* mp = mask + (row0 + row) * SEQ + pw * 32;
      uint32_t wd = 0;
      #pragma unroll
      for (int k = 0; k < 8; ++k) {
        i4 m = *(const i4*)(mp + k * 4);
        wd |= (uint32_t)(m.x != 0) << (k * 4);
        wd |= (uint32_t)(m.y != 0) << (k * 4 + 1);
        wd |= (uint32_t)(m.z != 0) << (k * 4 + 2);
        wd |= (uint32_t)(m.w != 0) << (k * 4 + 3);
      }
      bw[row][pw] = wd;
    }
    __syncthreads();
    const int qq = t & 63, pg = t >> 6;            // 4 pw-groups x 64 q
    uint32_t* bT = bitsT + (size_t)b * 128 * 4096 + qbase + qq;
    #pragma unroll 8
    for (int i = 0; i < 32; ++i) {
      int pw2 = pg * 32 + i;
      bT[(size_t)pw2 * 4096] = bw[qq][pw2];
    }
    return;
  }

  // ---- ctx GEMM, 64 rows ----
  float (*qs)[68]   = (float(*)[68])smem;
  float (*ws2)[136] = (float(*)[136])(smem + 8704);
  const int gb = blockIdx.x >> 1;                  // 0..511
  const int tx = t & 31, ty = t >> 5;
  const size_t row0 = (size_t)gb * 64;
  const int qr = t >> 2, qk = (t & 3) * 8;

  float acc[8][4];
  #pragma unroll
  for (int j = 0; j < 8; ++j)
    #pragma unroll
    for (int i = 0; i < 4; ++i) acc[j][i] = 0.f;

  for (int k0 = 0; k0 < DM; k0 += 32) {
    __syncthreads();
    {
      f32x4 v0 = *(const f32x4*)&q[(row0 + qr) * DM + k0 + qk];
      f32x4 v1 = *(const f32x4*)&q[(row0 + qr) * DM + k0 + qk + 4];
      #pragma unroll
      for (int i = 0; i < 4; ++i) qs[qk + i][qr] = v0[i];
      #pragma unroll
      for (int i = 0; i < 4; ++i) qs[qk + 4 + i][qr] = v1[i];
    }
    #pragma unroll
    for (int i = 0; i < 16; ++i) {
      int flat = t + i * 256;
      int kk = flat & 31, c = flat >> 5;
      ws2[kk][c] = (c < HD) ? wq[c * DM + k0 + kk] : 0.f;
    }
    __syncthreads();
    #pragma unroll
    for (int kk = 0; kk < 32; ++kk) {
      f32x4 bv = *(const f32x4*)&ws2[kk][tx * 4];
      f32x4 a0 = *(const f32x4*)&qs[kk][ty * 8];
      f32x4 a1 = *(const f32x4*)&qs[kk][ty * 8 + 4];
      #pragma unroll
      for (int r = 0; r < 4; ++r)
        #pragma unroll
        for (int c = 0; c < 4; ++c) {
          acc[r][c]     = fmaf(a0[r], bv[c], acc[r][c]);
          acc[4 + r][c] = fmaf(a1[r], bv[c], acc[4 + r][c]);
        }
    }
  }

  float wtv[4], bqv[4];
  #pragma unroll
  for (int i = 0; i < 4; ++i) {
    int c = tx * 4 + i;
    wtv[i] = (c < HD) ? wt[c] : 0.f;
    bqv[i] = (c < HD) ? bq[c] : 0.f;
  }
  #pragma unroll
  for (int j = 0; j < 8; ++j) {
    int r = ty * 8 + j;
    float v[4]; float ss = 0.f;
    #pragma unroll
    for (int i = 0; i < 4; ++i) {
      v[i] = (acc[j][i] + bqv[i]) * wtv[i];
      ss = fmaf(v[i], v[i], ss);
    }
    #pragma unroll
    for (int xm = 1; xm < 32; xm <<= 1) ss += __shfl_xor(ss, xm, 64);
    float rinv = 1.f / fmaxf(sqrtf(ss), 1e-12f);
    uint32_t p0 = (uint32_t)f2bf(v[0] * rinv) | ((uint32_t)f2bf(v[1] * rinv) << 16);
    uint32_t p1 = (uint32_t)f2bf(v[2] * rinv) | ((uint32_t)f2bf(v[3] * rinv) << 16);
    u32x2 o = {p0, p1};
    char* dst = (char*)ctx + (row0 + r) * 256 +
                (((tx >> 1) * 16) ^ ((r & 7) << 4)) + (tx & 1) * 8;
    *(u32x2*)dst = o;
  }
}

// -------------------------------------------------------------------------
// attn: R5 pipeline, p-split into two kernels for 2x grid parallelism.
// Block = 64 q-rows x 2048 p (1024 blocks, 4 blocks/CU). 4 waves share a
// double-buffered 64-p-row LDS tile, REG-STAGED (global->reg->ds_write);
// BAR = lgkmcnt(0) + s_barrier only (no vmcnt(0) in loop). 16x16x32 MFMA
// transposed D[p][q]: lane = q-row (ln), p contiguous per acc. Fixed
// softmax max = 1.0. A: l-partials to ws; B: scale + plain f32x4 stores.
// -------------------------------------------------------------------------
#define MFMA(A, B, C) __builtin_amdgcn_mfma_f32_16x16x32_bf16(A, B, C, 0, 0, 0)

static __device__ __forceinline__ v8bf ldfrag(const char* base, int row, int slot) {
  int byte = row * 256 + ((slot * 16) ^ ((row & 7) << 4));
  return __builtin_bit_cast(v8bf, *(const u32x4*)(base + byte));
}

#define STG_LOAD(R, j) do {                                                   \
  const char* _g = ctxb + (size_t)(P0 + (j) * 64) * 256 + w * 4096 + lane * 16;\
  R##0 = *(const u32x4*)(_g);        R##1 = *(const u32x4*)(_g + 1024);       \
  R##2 = *(const u32x4*)(_g + 2048); R##3 = *(const u32x4*)(_g + 3072);       \
} while (0)

#define STG_WRITE(R, buf) do {                                                \
  char* _l = (buf) + w * 4096 + lane * 16;                                    \
  *(u32x4*)(_l)        = R##0;  *(u32x4*)(_l + 1024) = R##1;                  \
  *(u32x4*)(_l + 2048) = R##2;  *(u32x4*)(_l + 3072) = R##3;                  \
} while (0)

#define QKT(buf, acc) do {                                                    \
  _Pragma("unroll")                                                           \
  for (int _t = 0; _t < 4; ++_t) {                                            \
    acc[_t] = (v4f){0.f, 0.f, 0.f, 0.f};                                      \
    _Pragma("unroll")                                                         \
    for (int _k = 0; _k < 4; ++_k) {                                          \
      v8bf _a = ldfrag(buf, _t * 16 + ln, _k * 4 + g);                        \
      acc[_t] = MFMA(_a, qf[_k], acc[_t]);                                    \
    }                                                                         \
  }                                                                           \
} while (0)

#define LDB(x, y, tj) do {                                                    \
  x = btb[(size_t)(tj) * 2 * 4096];                                           \
  y = btb[((size_t)(tj) * 2 + 1) * 4096];                                     \
} while (0)

#define EPIA() do {                                                           \
  _Pragma("unroll")                                                           \
  for (int _t2 = 0; _t2 < 4; ++_t2) {                                         \
    uint32_t nib = ((_t2 < 2 ? bcx : bcy) >> ((_t2 & 1) * 16 + g * 4));       \
    _Pragma("unroll")                                                         \
    for (int _i = 0; _i < 4; ++_i) {                                          \
      float e = __expf(acc[_t2][_i] - 1.0f);                                  \
      lsum += ((nib >> _i) & 1u) ? e : 0.f;                                   \
    }                                                                         \
  }                                                                           \
} while (0)

#define EPIB(tj) do {                                                         \
  _Pragma("unroll")                                                           \
  for (int _t2 = 0; _t2 < 4; ++_t2) {                                         \
    uint32_t nib = ((_t2 < 2 ? bcx : bcy) >> ((_t2 & 1) * 16 + g * 4));       \
    f32x4 o;                                                                  \
    _Pragma("unroll")                                                         \
    for (int _i = 0; _i < 4; ++_i)                                            \
      o[_i] = ((nib >> _i) & 1u) ? __expf(acc[_t2][_i] - 1.0f) * lir : 0.f;   \
    *(f32x4*)(orow + (size_t)(tj) * 64 + _t2 * 16 + g * 4) = o;               \
  }                                                                           \
} while (0)

#define BAR() do {                                                            \
  asm volatile("s_waitcnt lgkmcnt(0)" ::: "memory");                          \
  __builtin_amdgcn_s_barrier();                                               \
  __builtin_amdgcn_sched_barrier(0);                                          \
} while (0)

#define ATTN_COMMON                                                           \
  __shared__ __align__(16) char lds[32768];                                   \
  char* B0 = lds;                                                             \
  char* B1 = lds + 16384;                                                     \
  const int t    = threadIdx.x;                                               \
  const int b    = blockIdx.x & 7;                                            \
  const int rest = blockIdx.x >> 3;                                           \
  const int ph   = rest & 1;                                                  \
  const int qg   = rest >> 1;                                                 \
  const int w    = t >> 6, lane = t & 63;                                     \
  const int ln   = lane & 15, g = lane >> 4;                                  \
  const int q0   = qg * 64;                                                   \
  const int P0   = ph * PH;                                                   \
  const int qrow = q0 + w * 16 + ln;                                          \
  const char* ctxb = (const char*)ctx + (size_t)b * SEQ * 256;                \
  const uint32_t* __restrict__ btb =                                          \
      bitsT + ((size_t)b * 128 + (P0 >> 5)) * 4096 + qrow;                    \
  v8bf qf[4];                                                                 \
  _Pragma("unroll")                                                           \
  for (int kk = 0; kk < 4; ++kk) {                                            \
    int slot = kk * 4 + g;                                                    \
    qf[kk] = *(const v8bf*)(ctxb + (size_t)qrow * 256 +                       \
                            ((slot * 16) ^ ((qrow & 7) << 4)));               \
  }                                                                           \
  u32x4 sA0, sA1, sA2, sA3, sB0, sB1, sB2, sB3;                               \
  uint32_t bcx, bcy, bnx = 0, bny = 0;

__global__ __launch_bounds__(256) void attnA_kernel(
    const ushort* __restrict__ ctx, const uint32_t* __restrict__ bitsT,
    float* __restrict__ lpart)
{
  ATTN_COMMON
  float lsum = 0.f;

  STG_LOAD(sA, 0);
  STG_WRITE(sA, B0);
  STG_LOAD(sB, 1);
  LDB(bcx, bcy, 0);
  __syncthreads();

  for (int jj = 0; jj < NT; jj += 2) {
    if (jj + 1 < NT) LDB(bnx, bny, jj + 1);
    if (jj + 2 < NT) STG_LOAD(sA, jj + 2);
    { v4f acc[4]; QKT(B0, acc); STG_WRITE(sB, B1); EPIA(); }
    BAR();
    bcx = bnx; bcy = bny;

    if (jj + 2 < NT) LDB(bnx, bny, jj + 2);
    if (jj + 3 < NT) STG_LOAD(sB, jj + 3);
    { v4f acc[4]; QKT(B1, acc); if (jj + 2 < NT) STG_WRITE(sA, B0); EPIA(); }
    BAR();
    bcx = bnx; bcy = bny;
  }

  // reduce over the 4 g-groups (same qrow), then one store per row
  lsum += __shfl_xor(lsum, 16, 64);
  lsum += __shfl_xor(lsum, 32, 64);
  if (g == 0)
    lpart[(size_t)ph * (BATCH * SEQ) + (size_t)b * SEQ + qrow] = lsum;
}

__global__ __launch_bounds__(256) void attnB_kernel(
    const ushort* __restrict__ ctx, const uint32_t* __restrict__ bitsT,
    const float* __restrict__ lpart, float* __restrict__ out)
{
  ATTN_COMMON
  const size_t grow = (size_t)b * SEQ + qrow;
  const float lf = lpart[grow] + lpart[(size_t)(BATCH * SEQ) + grow];
  const float lir = (lf > 0.f) ? (1.f / lf) : 0.f;
  float* __restrict__ orow = out + grow * SEQ + P0;

  STG_LOAD(sA, 0);
  STG_WRITE(sA, B0);
  STG_LOAD(sB, 1);
  LDB(bcx, bcy, 0);
  __syncthreads();

  for (int jj = 0; jj < NT; jj += 2) {
    if (jj + 1 < NT) LDB(bnx, bny, jj + 1);
    if (jj + 2 < NT) STG_LOAD(sA, jj + 2);
    { v4f acc[4]; QKT(B0, acc); STG_WRITE(sB, B1); EPIB(jj); }
    BAR();
    bcx = bnx; bcy = bny;

    if (jj + 2 < NT) LDB(bnx, bny, jj + 2);
    if (jj + 3 < NT) STG_LOAD(sB, jj + 3);
    { v4f acc[4]; QKT(B1, acc); if (jj + 2 < NT) STG_WRITE(sA, B0); EPIB(jj + 1); }
    BAR();
    bcx = bnx; bcy = bny;
  }
}

// -------------------------------------------------------------------------
extern "C" void kernel_launch(void* const* d_in, const int* in_sizes, int n_in,
                              void* d_out, int out_size, void* d_ws, size_t ws_size,
                              hipStream_t stream) {
  const float* query = (const float*)d_in[0];
  const int*   mask  = (const int*)d_in[1];
  const float* w_q   = (const float*)d_in[2];
  const float* b_q   = (const float*)d_in[3];
  const float* wt    = (const float*)d_in[4];
  float* out = (float*)d_out;

  ushort*   ctx   = (ushort*)d_ws;                               // 8.39 MB @0
  uint32_t* bitsT = (uint32_t*)((char*)d_ws + (9u << 20));       // 16.78 MB @9M
  float*    lpart = (float*)((char*)d_ws + (26u << 20));         // 256 KB @26M

  prep_kernel <<<dim3(1024), dim3(256), 0, stream>>>(query, w_q, b_q, wt, mask, ctx, bitsT);
  attnA_kernel<<<dim3(1024), dim3(256), 0, stream>>>(ctx, bitsT, lpart);
  attnB_kernel<<<dim3(1024), dim3(256), 0, stream>>>(ctx, bitsT, lpart, out);
}